// Round 19
// baseline (423.147 us; speedup 1.0000x reference)
//
#include <hip/hip_runtime.h>
#include <hip/hip_fp16.h>

#define NNODES 100000
#define NHALF 50000
#define NEDGES 1600000
#define DIM 128
#define NBK ((NNODES + 255) / 256)       // 391 buckets of 256 nodes
#define NCH 256                          // scatter blocks / edge chunks
#define CHUNK ((NEDGES + NCH - 1) / NCH) // 6250 edges per chunk
#define EBUF 6144                        // per-bucket LDS edge capacity (mean 4096)
#define LSTR 136                         // padded LDS stride (halfs)
#define NGR32 ((size_t)NNODES * 32)      // group-major stride (halfs): [4][N][32]
#define CSRSZ (NEDGES + NBK * 1600 + 64) // split-padded csr/packed2 capacity

typedef _Float16 f16x8 __attribute__((ext_vector_type(8)));
typedef float f32x4 __attribute__((ext_vector_type(4)));

__device__ __forceinline__ float leaky02(float t) { return t > 0.f ? t : 0.2f * t; }

union H8u  { uint2 u; __half2 h[2]; };
union H16u { uint4 u; __half2 h[4]; };

// group-major fp16 layout: elem(node,col) = buf[(col>>5)*NGR32 + node*32 + (col&31)]

// ============ one-time W pre-convert: wt16[l][n][k] = fp16(W_l[k][n]) ==
__global__ __launch_bounds__(256) void wprep(const float* __restrict__ W0,
                                             const float* __restrict__ W1,
                                             const float* __restrict__ W2,
                                             __half* __restrict__ wt) {
    int idx = blockIdx.x * 256 + threadIdx.x;
    if (idx >= 3 * 128 * 128) return;
    int l = idx >> 14, rem = idx & 16383;
    int nn = rem >> 7, k = rem & 127;
    const float* W = (l == 0) ? W0 : ((l == 1) ? W1 : W2);
    wt[idx] = __float2half_rn(W[k * 128 + nn]);
}

// ============ MFMA fp16 GEMM + fused attention dots ==================
// Epilogue: per-wave LDS transpose of the C-fragments (wave owns its 16
// As rows exclusively -> no barrier) -> 16B coalesced H stores.
template <bool XF16>
__global__ __launch_bounds__(256) void gemm_mfma(const float* __restrict__ X,
                                                 const __half* __restrict__ X16,
                                                 const __half* __restrict__ wt16,
                                                 const float* __restrict__ as_,
                                                 const float* __restrict__ ad_,
                                                 __half* __restrict__ H,
                                                 float* __restrict__ s,
                                                 float* __restrict__ d, int n) {
    __shared__ __half As[64][LSTR];
    __shared__ __half Wt[128][LSTR];
    int t = threadIdx.x;
    int brow = blockIdx.x * 64;

    if (XF16) {
        for (int i = t; i < 64 * 16; i += 256) {
            int r = i >> 4, c8 = (i & 15) * 8;
            int gr = brow + r;
            int g = c8 >> 5, off = c8 & 31;
            uint4 v = (gr < n) ? *(const uint4*)(X16 + (size_t)g * NGR32 + (size_t)gr * 32 + off)
                               : make_uint4(0u, 0u, 0u, 0u);
            *(uint4*)&As[r][c8] = v;
        }
    } else {
        for (int i = t; i < 64 * 32; i += 256) {
            int r = i >> 5, c4 = (i & 31) * 4;
            int gr = brow + r;
            float4 v = (gr < n) ? *(const float4*)(X + (size_t)gr * 128 + c4)
                                : make_float4(0.f, 0.f, 0.f, 0.f);
            As[r][c4 + 0] = __float2half_rn(v.x);
            As[r][c4 + 1] = __float2half_rn(v.y);
            As[r][c4 + 2] = __float2half_rn(v.z);
            As[r][c4 + 3] = __float2half_rn(v.w);
        }
    }
    for (int i = t; i < 128 * 16; i += 256) {
        int r = i >> 4, c8 = (i & 15) * 8;
        *(uint4*)&Wt[r][c8] = *(const uint4*)(wt16 + r * 128 + c8);
    }
    __syncthreads();

    int wid  = t >> 6;
    int lane = t & 63;
    int lrow = lane & 15;
    int lkg  = lane >> 4;
    int r0   = wid * 16;

    f32x4 acc[8] = {};
#pragma unroll
    for (int kk = 0; kk < 128; kk += 32) {
        f16x8 af = *(const f16x8*)&As[r0 + lrow][kk + lkg * 8];
#pragma unroll
        for (int ct = 0; ct < 8; ++ct) {
            f16x8 bf = *(const f16x8*)&Wt[ct * 16 + lrow][kk + lkg * 8];
            acc[ct] = __builtin_amdgcn_mfma_f32_16x16x32_f16(af, bf, acc[ct], 0, 0, 0);
        }
    }

    // fused dots partials (register-only)
    float sp[4] = {0.f, 0.f, 0.f, 0.f};
    float dp[4] = {0.f, 0.f, 0.f, 0.f};
#pragma unroll
    for (int ct = 0; ct < 8; ++ct) {
        float a_s = as_[ct * 16 + lrow];
        float a_d = ad_[ct * 16 + lrow];
#pragma unroll
        for (int j = 0; j < 4; ++j) {
            sp[j] += acc[ct][j] * a_s;
            dp[j] += acc[ct][j] * a_d;
        }
    }

    // per-wave LDS transpose: acc -> As rows r0..r0+15 (exclusive to wave)
#pragma unroll
    for (int ct = 0; ct < 8; ++ct)
#pragma unroll
        for (int j = 0; j < 4; ++j)
            As[r0 + lkg * 4 + j][ct * 16 + lrow] = __float2half_rn(acc[ct][j]);
    // read back 16B chunks, store coalesced (lanes 0..3 = one 64B line)
#pragma unroll
    for (int c = 0; c < 4; ++c) {
        int idx = c * 64 + lane;
        int row16 = idx >> 4;            // 0..15
        int chunk = idx & 15;            // 16 halfs-chunks of 8
        int gr = brow + r0 + row16;
        if (gr < n) {
            uint4 v = *(const uint4*)&As[r0 + row16][chunk * 8];
            int g = chunk >> 2, off = (chunk & 3) * 8;
            *(uint4*)(H + (size_t)g * NGR32 + (size_t)gr * 32 + off) = v;
        }
    }

#pragma unroll
    for (int off = 1; off < 16; off <<= 1)
#pragma unroll
        for (int j = 0; j < 4; ++j) {
            sp[j] += __shfl_xor(sp[j], off);
            dp[j] += __shfl_xor(dp[j], off);
        }
    if (lrow == 0)
#pragma unroll
        for (int j = 0; j < 4; ++j) {
            int gr = brow + r0 + lkg * 4 + j;
            if (gr < n) { s[gr] = sp[j]; d[gr] = dp[j]; }
        }
}

// ============ bucket-sort CSR build (no global atomics) =============
__global__ __launch_bounds__(512) void bucket_count(const int* __restrict__ dst,
                                                    int* __restrict__ blockcounts) {
    __shared__ int hist[NBK];
    int b = blockIdx.x, t = threadIdx.x;
    for (int i = t; i < NBK; i += 512) hist[i] = 0;
    __syncthreads();
    int e0 = b * CHUNK, e1 = min(NEDGES, e0 + CHUNK);
    for (int e = e0 + t; e < e1; e += 512)
        atomicAdd(&hist[dst[e] >> 8], 1);
    __syncthreads();
    for (int i = t; i < NBK; i += 512)
        blockcounts[i * NCH + b] = hist[i];
}

// per-bucket exclusive scan over NCH=256 chunk counts (256-thread block scan)
__global__ __launch_bounds__(NCH) void bucket_scan_a(int* __restrict__ blockcounts,
                                                     int* __restrict__ btotal) {
    int bin = blockIdx.x, t = threadIdx.x;
    int v = blockcounts[bin * NCH + t];
    int incl = v;
#pragma unroll
    for (int off = 1; off < 64; off <<= 1) {
        int u = __shfl_up(incl, off, 64);
        if ((t & 63) >= off) incl += u;
    }
    __shared__ int wsum[NCH / 64], woff[NCH / 64];
    if ((t & 63) == 63) wsum[t >> 6] = incl;
    __syncthreads();
    if (t == 0) {
        int run = 0;
#pragma unroll
        for (int w = 0; w < NCH / 64; ++w) { woff[w] = run; run += wsum[w]; }
    }
    __syncthreads();
    int excl = incl - v + woff[t >> 6];
    blockcounts[bin * NCH + t] = excl;
    if (t == NCH - 1) btotal[bin] = excl + v;
}

// scan NBK=391 bucket totals -> bbase (one block, 512 threads)
__global__ __launch_bounds__(512) void bucket_scan_b(const int* __restrict__ btotal,
                                                     int* __restrict__ bbase) {
    int t = threadIdx.x;
    int v = (t < NBK) ? btotal[t] : 0;
    int incl = v;
#pragma unroll
    for (int off = 1; off < 64; off <<= 1) {
        int u = __shfl_up(incl, off, 64);
        if ((t & 63) >= off) incl += u;
    }
    __shared__ int wsum[8], woff[8];
    if ((t & 63) == 63) wsum[t >> 6] = incl;
    __syncthreads();
    if (t == 0) {
        int run = 0;
#pragma unroll
        for (int w = 0; w < 8; ++w) { woff[w] = run; run += wsum[w]; }
    }
    __syncthreads();
    int excl = incl - v + woff[t >> 6];
    if (t < NBK) bbase[t] = excl;
    if (t == NBK - 1) bbase[NBK] = excl + v;
}

__global__ __launch_bounds__(512) void bucket_scatter(const int* __restrict__ src,
                                                      const int* __restrict__ dst,
                                                      const int* __restrict__ blockcounts,
                                                      const int* __restrict__ bbase,
                                                      int* __restrict__ packed) {
    __shared__ int cur[NBK];
    int b = blockIdx.x, t = threadIdx.x;
    for (int i = t; i < NBK; i += 512) cur[i] = bbase[i] + blockcounts[i * NCH + b];
    __syncthreads();
    int e0 = b * CHUNK, e1 = min(NEDGES, e0 + CHUNK);
    for (int e = e0 + t; e < e1; e += 512) {
        int dv = dst[e];
        int bin = dv >> 8;
        int p = atomicAdd(&cur[bin], 1);
        packed[p] = ((dv & 255) << 17) | src[e];
    }
}

// pass 4: per-bucket (256 nodes) count/scan -> SRC-SPLIT padded csr.
// Each node's list: [low reals | pads->x4 | high reals | pads->x4];
// self inline in its half. cnts[node] = cl | (ch<<16).
__global__ __launch_bounds__(256) void bucket_csr(const int* __restrict__ packed,
                                                  const int* __restrict__ bbase,
                                                  int* __restrict__ rowptr4,
                                                  int* __restrict__ cnts,
                                                  int* __restrict__ csr_src) {
    __shared__ int ebuf[EBUF];
    __shared__ int hist[256], histL[256], curL[256], curH[256];
    __shared__ int wsum[4], woff[4];
    int i = blockIdx.x, t = threadIdx.x;
    int base_in = bbase[i], cnt = bbase[i + 1] - base_in;
    int pbase = ((base_in + 3) & ~3) + i * 1600;   // split pads <= 6/node
    bool inl = (cnt <= EBUF);
    if (inl) for (int j = t; j < cnt; j += 256) ebuf[j] = packed[base_in + j];
    hist[t] = 0; histL[t] = 0;
    __syncthreads();
    for (int j = t; j < cnt; j += 256) {
        int v = inl ? ebuf[j] : packed[base_in + j];
        int nid = v >> 17;
        atomicAdd(&hist[nid], 1);
        if ((v & 0x1FFFF) < NHALF) atomicAdd(&histL[nid], 1);
    }
    __syncthreads();
    {
        int node = i * 256 + t;
        bool valid = node < NNODES;
        int h = hist[t], hl = histL[t];
        bool selfLow = valid && (node < NHALF);
        int cl = valid ? (hl + (selfLow ? 1 : 0)) : 0;
        int ch = valid ? ((h - hl) + (selfLow ? 0 : 1)) : 0;
        int c4l = (cl + 3) & ~3, c4h = (ch + 3) & ~3;
        int tot4 = c4l + c4h;
        int incl = tot4;
#pragma unroll
        for (int off = 1; off < 64; off <<= 1) {
            int u = __shfl_up(incl, off, 64);
            if ((t & 63) >= off) incl += u;
        }
        if ((t & 63) == 63) wsum[t >> 6] = incl;
        __syncthreads();
        if (t == 0) {
            int run = 0;
#pragma unroll
            for (int w = 0; w < 4; ++w) { woff[w] = run; run += wsum[w]; }
        }
        __syncthreads();
        int ex = incl - tot4 + woff[t >> 6];
        int nodebase = pbase + ex;
        curL[t] = nodebase;
        curH[t] = nodebase + c4l;
        if (valid) {
            rowptr4[node] = nodebase;
            cnts[node] = cl | (ch << 16);
            csr_src[selfLow ? (nodebase + hl) : (nodebase + c4l + (h - hl))] = node;
        }
    }
    __syncthreads();
    for (int j = t; j < cnt; j += 256) {
        int v = inl ? ebuf[j] : packed[base_in + j];
        int nid = v >> 17;
        int srcv = v & 0x1FFFF;
        int off = (srcv < NHALF) ? atomicAdd(&curL[nid], 1) : atomicAdd(&curH[nid], 1);
        csr_src[off] = srcv;
    }
}

// ============ per-edge normalized attention over the split list =======
// packed2[slot] = (src<<15)|q15(alpha); pads: low half src=0, high src=NHALF.
__global__ __launch_bounds__(256) void gat_alpha(const int* __restrict__ rowptr4,
                                                 const int* __restrict__ cnts,
                                                 const int* __restrict__ csr,
                                                 const float* __restrict__ s,
                                                 const float* __restrict__ d,
                                                 unsigned* __restrict__ packed2, int n) {
    int node = blockIdx.x * 8 + (threadIdx.x >> 5);
    if (node >= n) return;
    int lane = threadIdx.x & 31;
    int base = rowptr4[node];
    int cw = cnts[node];
    int cl = cw & 0xFFFF, ch = cw >> 16;
    int c4l = (cl + 3) & ~3, c4h = (ch + 3) & ~3;
    int tot = c4l + c4h;
    float dnode = d[node];

    if (tot <= 32) {
        bool real = (lane < cl) || (lane >= c4l && lane < c4l + ch);
        int si = real ? csr[base + lane] : 0;
        float lv = real ? leaky02(s[si] + dnode) : -1e30f;
        float lm = lv;
#pragma unroll
        for (int off = 16; off; off >>= 1) lm = fmaxf(lm, __shfl_xor(lm, off));
        float w = real ? expf(lv - lm) : 0.f;
        float denom = w;
#pragma unroll
        for (int off = 16; off; off >>= 1) denom += __shfl_xor(denom, off);
        if (lane < tot) {
            unsigned pk = real ? (((unsigned)si << 15) |
                                  (unsigned)__float2int_rn(w / denom * 32767.f))
                               : (lane < c4l ? 0u : ((unsigned)NHALF << 15));
            packed2[base + lane] = pk;
        }
    } else {
        float m = -1e30f;
        for (int c = 0; c < tot; c += 32) {
            int idx = c + lane;
            bool real = (idx < cl) || (idx >= c4l && idx < c4l + ch);
            int si = real ? csr[base + idx] : 0;
            float lv = real ? leaky02(s[si] + dnode) : -1e30f;
            m = fmaxf(m, lv);
        }
#pragma unroll
        for (int off = 16; off; off >>= 1) m = fmaxf(m, __shfl_xor(m, off));
        float denom = 0.f;
        for (int c = 0; c < tot; c += 32) {
            int idx = c + lane;
            bool real = (idx < cl) || (idx >= c4l && idx < c4l + ch);
            int si = real ? csr[base + idx] : 0;
            if (real) denom += expf(leaky02(s[si] + dnode) - m);
        }
#pragma unroll
        for (int off = 16; off; off >>= 1) denom += __shfl_xor(denom, off);
        for (int c = 0; c < tot; c += 32) {
            int idx = c + lane;
            if (idx < tot) {
                bool real = (idx < cl) || (idx >= c4l && idx < c4l + ch);
                int si = real ? csr[base + idx] : 0;
                unsigned pk;
                if (real) {
                    float w = expf(leaky02(s[si] + dnode) - m);
                    pk = ((unsigned)si << 15) |
                         (unsigned)__float2int_rn(w / denom * 32767.f);
                } else {
                    pk = (idx < c4l) ? 0u : ((unsigned)NHALF << 15);
                }
                packed2[base + idx] = pk;
            }
        }
    }
}

// ============ grouped aggregation, src-split two-pass, 8-slot MLP =====
// group = blockIdx & 3; pass 0: low-src half -> partial in A16 (no bias);
// pass 1: high-src half + partial -> bias + relu -> A16.
// Per (group,pass) H working set = 50k x 64B = 3.2MB -> L2-resident.
// 8 independent H-row loads in flight per lane; tail quad masked by mB.
template <int PASS>
__global__ __launch_bounds__(256) void gat_agg(const int* __restrict__ rowptr4,
                                               const int* __restrict__ cnts,
                                               const unsigned* __restrict__ packed2,
                                               const __half* __restrict__ H,
                                               const float* __restrict__ bias,
                                               __half* __restrict__ A16, int n) {
    int grp = blockIdx.x & 3;
    int blk = blockIdx.x >> 2;
    int wid = threadIdx.x >> 6;
    int lane = threadIdx.x & 63;
    int nd = lane >> 2;                  // node slot 0..15
    int cg = lane & 3;                   // col sub-group: 8 cols (16B)
    int node = blk * 64 + wid * 16 + nd;
    if (node >= n) return;
    const __half* Hs = H + (size_t)grp * NGR32 + cg * 8;
    __half* As = A16 + (size_t)grp * NGR32;

    int base = rowptr4[node];
    int cw   = cnts[node];
    int cl = cw & 0xFFFF, ch = cw >> 16;
    int q4, off0;
    if (PASS == 0) { q4 = (cl + 3) >> 2; off0 = 0; }
    else           { q4 = (ch + 3) >> 2; off0 = (cl + 3) & ~3; }
    int iters = (q4 + 1) >> 1;
    const uint4* p = (const uint4*)(packed2 + base + off0);

    // pass-1: partial load (independent, overlaps the loop)
    H16u part;
    if (PASS == 1) part.u = *(const uint4*)(As + (size_t)node * 32 + cg * 8);

    float acc[8] = {0.f, 0.f, 0.f, 0.f, 0.f, 0.f, 0.f, 0.f};
    for (int it = 0; it < iters; ++it) {
        uint4 qa = p[2 * it];
        uint4 qb = p[2 * it + 1];        // may be junk quad: masked by mB
        float mB = (2 * it + 1 < q4) ? 1.f : 0.f;
        float a0 = (float)(qa.x & 0x7fffu);
        float a1 = (float)(qa.y & 0x7fffu);
        float a2 = (float)(qa.z & 0x7fffu);
        float a3 = (float)(qa.w & 0x7fffu);
        float b0 = (float)(qb.x & 0x7fffu) * mB;
        float b1 = (float)(qb.y & 0x7fffu) * mB;
        float b2 = (float)(qb.z & 0x7fffu) * mB;
        float b3 = (float)(qb.w & 0x7fffu) * mB;
        H16u h0, h1, h2, h3, h4, h5, h6, h7;
        h0.u = *(const uint4*)(Hs + (size_t)(qa.x >> 15) * 32);
        h1.u = *(const uint4*)(Hs + (size_t)(qa.y >> 15) * 32);
        h2.u = *(const uint4*)(Hs + (size_t)(qa.z >> 15) * 32);
        h3.u = *(const uint4*)(Hs + (size_t)(qa.w >> 15) * 32);
        h4.u = *(const uint4*)(Hs + (size_t)(qb.x >> 15) * 32);
        h5.u = *(const uint4*)(Hs + (size_t)(qb.y >> 15) * 32);
        h6.u = *(const uint4*)(Hs + (size_t)(qb.z >> 15) * 32);
        h7.u = *(const uint4*)(Hs + (size_t)(qb.w >> 15) * 32);
#pragma unroll
        for (int c2 = 0; c2 < 4; ++c2) {
            float2 f0 = __half22float2(h0.h[c2]);
            float2 f1 = __half22float2(h1.h[c2]);
            float2 f2 = __half22float2(h2.h[c2]);
            float2 f3 = __half22float2(h3.h[c2]);
            float2 f4 = __half22float2(h4.h[c2]);
            float2 f5 = __half22float2(h5.h[c2]);
            float2 f6 = __half22float2(h6.h[c2]);
            float2 f7 = __half22float2(h7.h[c2]);
            acc[c2 * 2 + 0] += a0 * f0.x + a1 * f1.x + a2 * f2.x + a3 * f3.x
                             + b0 * f4.x + b1 * f5.x + b2 * f6.x + b3 * f7.x;
            acc[c2 * 2 + 1] += a0 * f0.y + a1 * f1.y + a2 * f2.y + a3 * f3.y
                             + b0 * f4.y + b1 * f5.y + b2 * f6.y + b3 * f7.y;
        }
    }
    const float scale = 1.f / 32767.f;
    H16u pk16;
    if (PASS == 0) {
#pragma unroll
        for (int c2 = 0; c2 < 4; ++c2)
            pk16.h[c2] = __floats2half2_rn(acc[c2 * 2 + 0] * scale,
                                           acc[c2 * 2 + 1] * scale);
    } else {
        int cb = grp * 32 + cg * 8;
#pragma unroll
        for (int c2 = 0; c2 < 4; ++c2) {
            float2 pv = __half22float2(part.h[c2]);
            float o0 = fmaxf(pv.x + acc[c2 * 2 + 0] * scale + bias[cb + c2 * 2 + 0], 0.f);
            float o1 = fmaxf(pv.y + acc[c2 * 2 + 1] * scale + bias[cb + c2 * 2 + 1], 0.f);
            pk16.h[c2] = __floats2half2_rn(o0, o1);
        }
    }
    *(uint4*)(As + (size_t)node * 32 + cg * 8) = pk16.u;
}

// ============ classifier: out = A16 @ Wc + bc  (A16 group-major) ======
__global__ __launch_bounds__(256) void classify16(const __half* __restrict__ A,
                                                  const float* __restrict__ Wc,
                                                  const float* __restrict__ bc,
                                                  float* __restrict__ out, int n) {
    int node = blockIdx.x * 4 + (threadIdx.x >> 6);
    if (node >= n) return;
    int lane = threadIdx.x & 63;
    int col = lane * 2;
    int g = col >> 5, off = col & 31;
    __half2 h2 = *(const __half2*)(A + (size_t)g * NGR32 + (size_t)node * 32 + off);
    float2 f = __half22float2(h2);
    float o0 = f.x * Wc[col * 2]       + f.y * Wc[(col + 1) * 2];
    float o1 = f.x * Wc[col * 2 + 1]   + f.y * Wc[(col + 1) * 2 + 1];
#pragma unroll
    for (int offx = 32; offx; offx >>= 1) {
        o0 += __shfl_xor(o0, offx);
        o1 += __shfl_xor(o1, offx);
    }
    if (lane == 0) {
        out[(size_t)node * 2 + 0] = o0 + bc[0];
        out[(size_t)node * 2 + 1] = o1 + bc[1];
    }
}

extern "C" void kernel_launch(void* const* d_in, const int* in_sizes, int n_in,
                              void* d_out, int out_size, void* d_ws, size_t ws_size,
                              hipStream_t stream) {
    const float* x   = (const float*)d_in[0];
    const int*   ei  = (const int*)d_in[1];
    const int*   src = ei;
    const int*   dst = ei + NEDGES;
    const float* Ws[3]  = {(const float*)d_in[2], (const float*)d_in[6], (const float*)d_in[10]};
    const float* ass[3] = {(const float*)d_in[3], (const float*)d_in[7], (const float*)d_in[11]};
    const float* ads[3] = {(const float*)d_in[4], (const float*)d_in[8], (const float*)d_in[12]};
    const float* bs[3]  = {(const float*)d_in[5], (const float*)d_in[9], (const float*)d_in[13]};
    const float* Wc = (const float*)d_in[14];
    const float* bc = (const float*)d_in[15];
    float* out = (float*)d_out;

    const int n = NNODES;

    // ---- workspace (~80 MB) ----
    __half*   h16  = (__half*)d_ws;                     // N*128 fp16 (group-major)
    __half*   a16  = h16 + (size_t)n * DIM;             // N*128 fp16 (group-major)
    __half*   wt16 = a16 + (size_t)n * DIM;             // 3*128*128 fp16 (W^T)
    float*    sbuf = (float*)(wt16 + 3 * 128 * 128);    // N
    float*    dbuf = sbuf + n;                          // N
    int*      rowptr4     = (int*)(dbuf + n);           // N
    int*      cnts        = rowptr4 + n;                // N
    int*      csr_src     = cnts + n;                   // CSRSZ
    unsigned* packed2     = (unsigned*)(csr_src + CSRSZ); // CSRSZ
    int*      packed      = (int*)(packed2 + CSRSZ);    // E (build temp)
    int*      blockcounts = packed + NEDGES;            // NBK*NCH
    int*      bbase       = blockcounts + (size_t)NBK * NCH; // NBK+1
    int*      btotal      = bbase + NBK + 1;            // NBK

    const int g64        = (n + 63) / 64;
    const int alpha_grid = (n + 7) / 8;           // 12500
    const int cls_grid   = (n + 3) / 4;           // 25000
    const int agg_grid   = ((n + 63) / 64) * 4;   // 6252

    // ---- one-time prep ----
    wprep<<<192, 256, 0, stream>>>(Ws[0], Ws[1], Ws[2], wt16);
    bucket_count<<<NCH, 512, 0, stream>>>(dst, blockcounts);
    bucket_scan_a<<<NBK, NCH, 0, stream>>>(blockcounts, btotal);
    bucket_scan_b<<<1, 512, 0, stream>>>(btotal, bbase);
    bucket_scatter<<<NCH, 512, 0, stream>>>(src, dst, blockcounts, bbase, packed);
    bucket_csr<<<NBK, 256, 0, stream>>>(packed, bbase, rowptr4, cnts, csr_src);

    // ---- 3 GAT layers ----
    for (int layer = 0; layer < 3; ++layer) {
        const __half* wl = wt16 + (size_t)layer * 128 * 128;
        if (layer == 0)
            gemm_mfma<false><<<g64, 256, 0, stream>>>(x, a16, wl, ass[0], ads[0],
                                                      h16, sbuf, dbuf, n);
        else
            gemm_mfma<true><<<g64, 256, 0, stream>>>(x, a16, wl, ass[layer], ads[layer],
                                                     h16, sbuf, dbuf, n);
        gat_alpha<<<alpha_grid, 256, 0, stream>>>(rowptr4, cnts, csr_src, sbuf, dbuf,
                                                  packed2, n);
        gat_agg<0><<<agg_grid, 256, 0, stream>>>(rowptr4, cnts, packed2, h16, bs[layer], a16, n);
        gat_agg<1><<<agg_grid, 256, 0, stream>>>(rowptr4, cnts, packed2, h16, bs[layer], a16, n);
    }
    classify16<<<cls_grid, 256, 0, stream>>>(a16, Wc, bc, out, n);
}

// Round 20
// 364.029 us; speedup vs baseline: 1.1624x; 1.1624x over previous
//
#include <hip/hip_runtime.h>
#include <hip/hip_fp16.h>

#define NNODES 100000
#define NHALF 50000
#define NEDGES 1600000
#define DIM 128
#define NBK ((NNODES + 255) / 256)       // 391 buckets of 256 nodes
#define NCH 256                          // scatter blocks / edge chunks
#define CHUNK ((NEDGES + NCH - 1) / NCH) // 6250 edges per chunk
#define EBUF 6144                        // per-bucket LDS edge capacity (mean 4096)
#define LSTR 136                         // padded LDS stride (halfs)
#define NGR32 ((size_t)NNODES * 32)      // group-major stride (halfs): [4][N][32]
#define CSRSZ (NEDGES + NBK * 1600 + 64) // split-padded csr/packed2 capacity

typedef _Float16 f16x8 __attribute__((ext_vector_type(8)));
typedef float f32x4 __attribute__((ext_vector_type(4)));

__device__ __forceinline__ float leaky02(float t) { return t > 0.f ? t : 0.2f * t; }

union H8u  { uint2 u; __half2 h[2]; };
union H16u { uint4 u; __half2 h[4]; };

// group-major fp16 layout: elem(node,col) = buf[(col>>5)*NGR32 + node*32 + (col&31)]

// ============ one-time W pre-convert: wt16[l][n][k] = fp16(W_l[k][n]) ==
__global__ __launch_bounds__(256) void wprep(const float* __restrict__ W0,
                                             const float* __restrict__ W1,
                                             const float* __restrict__ W2,
                                             __half* __restrict__ wt) {
    int idx = blockIdx.x * 256 + threadIdx.x;
    if (idx >= 3 * 128 * 128) return;
    int l = idx >> 14, rem = idx & 16383;
    int nn = rem >> 7, k = rem & 127;
    const float* W = (l == 0) ? W0 : ((l == 1) ? W1 : W2);
    wt[idx] = __float2half_rn(W[k * 128 + nn]);
}

// ============ MFMA fp16 GEMM + fused attention dots ==================
// Epilogue: per-wave LDS transpose of the C-fragments (wave owns its 16
// As rows exclusively -> no barrier) -> 16B coalesced H stores.
template <bool XF16>
__global__ __launch_bounds__(256) void gemm_mfma(const float* __restrict__ X,
                                                 const __half* __restrict__ X16,
                                                 const __half* __restrict__ wt16,
                                                 const float* __restrict__ as_,
                                                 const float* __restrict__ ad_,
                                                 __half* __restrict__ H,
                                                 float* __restrict__ s,
                                                 float* __restrict__ d, int n) {
    __shared__ __half As[64][LSTR];
    __shared__ __half Wt[128][LSTR];
    int t = threadIdx.x;
    int brow = blockIdx.x * 64;

    if (XF16) {
        for (int i = t; i < 64 * 16; i += 256) {
            int r = i >> 4, c8 = (i & 15) * 8;
            int gr = brow + r;
            int g = c8 >> 5, off = c8 & 31;
            uint4 v = (gr < n) ? *(const uint4*)(X16 + (size_t)g * NGR32 + (size_t)gr * 32 + off)
                               : make_uint4(0u, 0u, 0u, 0u);
            *(uint4*)&As[r][c8] = v;
        }
    } else {
        for (int i = t; i < 64 * 32; i += 256) {
            int r = i >> 5, c4 = (i & 31) * 4;
            int gr = brow + r;
            float4 v = (gr < n) ? *(const float4*)(X + (size_t)gr * 128 + c4)
                                : make_float4(0.f, 0.f, 0.f, 0.f);
            As[r][c4 + 0] = __float2half_rn(v.x);
            As[r][c4 + 1] = __float2half_rn(v.y);
            As[r][c4 + 2] = __float2half_rn(v.z);
            As[r][c4 + 3] = __float2half_rn(v.w);
        }
    }
    for (int i = t; i < 128 * 16; i += 256) {
        int r = i >> 4, c8 = (i & 15) * 8;
        *(uint4*)&Wt[r][c8] = *(const uint4*)(wt16 + r * 128 + c8);
    }
    __syncthreads();

    int wid  = t >> 6;
    int lane = t & 63;
    int lrow = lane & 15;
    int lkg  = lane >> 4;
    int r0   = wid * 16;

    f32x4 acc[8] = {};
#pragma unroll
    for (int kk = 0; kk < 128; kk += 32) {
        f16x8 af = *(const f16x8*)&As[r0 + lrow][kk + lkg * 8];
#pragma unroll
        for (int ct = 0; ct < 8; ++ct) {
            f16x8 bf = *(const f16x8*)&Wt[ct * 16 + lrow][kk + lkg * 8];
            acc[ct] = __builtin_amdgcn_mfma_f32_16x16x32_f16(af, bf, acc[ct], 0, 0, 0);
        }
    }

    // fused dots partials (register-only)
    float sp[4] = {0.f, 0.f, 0.f, 0.f};
    float dp[4] = {0.f, 0.f, 0.f, 0.f};
#pragma unroll
    for (int ct = 0; ct < 8; ++ct) {
        float a_s = as_[ct * 16 + lrow];
        float a_d = ad_[ct * 16 + lrow];
#pragma unroll
        for (int j = 0; j < 4; ++j) {
            sp[j] += acc[ct][j] * a_s;
            dp[j] += acc[ct][j] * a_d;
        }
    }

    // per-wave LDS transpose: acc -> As rows r0..r0+15 (exclusive to wave)
#pragma unroll
    for (int ct = 0; ct < 8; ++ct)
#pragma unroll
        for (int j = 0; j < 4; ++j)
            As[r0 + lkg * 4 + j][ct * 16 + lrow] = __float2half_rn(acc[ct][j]);
    // read back 16B chunks, store coalesced (lanes 0..3 = one 64B line)
#pragma unroll
    for (int c = 0; c < 4; ++c) {
        int idx = c * 64 + lane;
        int row16 = idx >> 4;            // 0..15
        int chunk = idx & 15;            // 16 halfs-chunks of 8
        int gr = brow + r0 + row16;
        if (gr < n) {
            uint4 v = *(const uint4*)&As[r0 + row16][chunk * 8];
            int g = chunk >> 2, off = (chunk & 3) * 8;
            *(uint4*)(H + (size_t)g * NGR32 + (size_t)gr * 32 + off) = v;
        }
    }

#pragma unroll
    for (int off = 1; off < 16; off <<= 1)
#pragma unroll
        for (int j = 0; j < 4; ++j) {
            sp[j] += __shfl_xor(sp[j], off);
            dp[j] += __shfl_xor(dp[j], off);
        }
    if (lrow == 0)
#pragma unroll
        for (int j = 0; j < 4; ++j) {
            int gr = brow + r0 + lkg * 4 + j;
            if (gr < n) { s[gr] = sp[j]; d[gr] = dp[j]; }
        }
}

// ============ bucket-sort CSR build (no global atomics) =============
__global__ __launch_bounds__(512) void bucket_count(const int* __restrict__ dst,
                                                    int* __restrict__ blockcounts) {
    __shared__ int hist[NBK];
    int b = blockIdx.x, t = threadIdx.x;
    for (int i = t; i < NBK; i += 512) hist[i] = 0;
    __syncthreads();
    int e0 = b * CHUNK, e1 = min(NEDGES, e0 + CHUNK);
    for (int e = e0 + t; e < e1; e += 512)
        atomicAdd(&hist[dst[e] >> 8], 1);
    __syncthreads();
    for (int i = t; i < NBK; i += 512)
        blockcounts[i * NCH + b] = hist[i];
}

// per-bucket exclusive scan over NCH=256 chunk counts (256-thread block scan)
__global__ __launch_bounds__(NCH) void bucket_scan_a(int* __restrict__ blockcounts,
                                                     int* __restrict__ btotal) {
    int bin = blockIdx.x, t = threadIdx.x;
    int v = blockcounts[bin * NCH + t];
    int incl = v;
#pragma unroll
    for (int off = 1; off < 64; off <<= 1) {
        int u = __shfl_up(incl, off, 64);
        if ((t & 63) >= off) incl += u;
    }
    __shared__ int wsum[NCH / 64], woff[NCH / 64];
    if ((t & 63) == 63) wsum[t >> 6] = incl;
    __syncthreads();
    if (t == 0) {
        int run = 0;
#pragma unroll
        for (int w = 0; w < NCH / 64; ++w) { woff[w] = run; run += wsum[w]; }
    }
    __syncthreads();
    int excl = incl - v + woff[t >> 6];
    blockcounts[bin * NCH + t] = excl;
    if (t == NCH - 1) btotal[bin] = excl + v;
}

// scan NBK=391 bucket totals -> bbase (one block, 512 threads)
__global__ __launch_bounds__(512) void bucket_scan_b(const int* __restrict__ btotal,
                                                     int* __restrict__ bbase) {
    int t = threadIdx.x;
    int v = (t < NBK) ? btotal[t] : 0;
    int incl = v;
#pragma unroll
    for (int off = 1; off < 64; off <<= 1) {
        int u = __shfl_up(incl, off, 64);
        if ((t & 63) >= off) incl += u;
    }
    __shared__ int wsum[8], woff[8];
    if ((t & 63) == 63) wsum[t >> 6] = incl;
    __syncthreads();
    if (t == 0) {
        int run = 0;
#pragma unroll
        for (int w = 0; w < 8; ++w) { woff[w] = run; run += wsum[w]; }
    }
    __syncthreads();
    int excl = incl - v + woff[t >> 6];
    if (t < NBK) bbase[t] = excl;
    if (t == NBK - 1) bbase[NBK] = excl + v;
}

__global__ __launch_bounds__(512) void bucket_scatter(const int* __restrict__ src,
                                                      const int* __restrict__ dst,
                                                      const int* __restrict__ blockcounts,
                                                      const int* __restrict__ bbase,
                                                      int* __restrict__ packed) {
    __shared__ int cur[NBK];
    int b = blockIdx.x, t = threadIdx.x;
    for (int i = t; i < NBK; i += 512) cur[i] = bbase[i] + blockcounts[i * NCH + b];
    __syncthreads();
    int e0 = b * CHUNK, e1 = min(NEDGES, e0 + CHUNK);
    for (int e = e0 + t; e < e1; e += 512) {
        int dv = dst[e];
        int bin = dv >> 8;
        int p = atomicAdd(&cur[bin], 1);
        packed[p] = ((dv & 255) << 17) | src[e];
    }
}

// pass 4: per-bucket (256 nodes) count/scan -> SRC-SPLIT padded csr.
// Each node's list: [low reals | pads->x4 | high reals | pads->x4];
// self inline in its half. cnts[node] = cl | (ch<<16).
__global__ __launch_bounds__(256) void bucket_csr(const int* __restrict__ packed,
                                                  const int* __restrict__ bbase,
                                                  int* __restrict__ rowptr4,
                                                  int* __restrict__ cnts,
                                                  int* __restrict__ csr_src) {
    __shared__ int ebuf[EBUF];
    __shared__ int hist[256], histL[256], curL[256], curH[256];
    __shared__ int wsum[4], woff[4];
    int i = blockIdx.x, t = threadIdx.x;
    int base_in = bbase[i], cnt = bbase[i + 1] - base_in;
    int pbase = ((base_in + 3) & ~3) + i * 1600;   // split pads <= 6/node
    bool inl = (cnt <= EBUF);
    if (inl) for (int j = t; j < cnt; j += 256) ebuf[j] = packed[base_in + j];
    hist[t] = 0; histL[t] = 0;
    __syncthreads();
    for (int j = t; j < cnt; j += 256) {
        int v = inl ? ebuf[j] : packed[base_in + j];
        int nid = v >> 17;
        atomicAdd(&hist[nid], 1);
        if ((v & 0x1FFFF) < NHALF) atomicAdd(&histL[nid], 1);
    }
    __syncthreads();
    {
        int node = i * 256 + t;
        bool valid = node < NNODES;
        int h = hist[t], hl = histL[t];
        bool selfLow = valid && (node < NHALF);
        int cl = valid ? (hl + (selfLow ? 1 : 0)) : 0;
        int ch = valid ? ((h - hl) + (selfLow ? 0 : 1)) : 0;
        int c4l = (cl + 3) & ~3, c4h = (ch + 3) & ~3;
        int tot4 = c4l + c4h;
        int incl = tot4;
#pragma unroll
        for (int off = 1; off < 64; off <<= 1) {
            int u = __shfl_up(incl, off, 64);
            if ((t & 63) >= off) incl += u;
        }
        if ((t & 63) == 63) wsum[t >> 6] = incl;
        __syncthreads();
        if (t == 0) {
            int run = 0;
#pragma unroll
            for (int w = 0; w < 4; ++w) { woff[w] = run; run += wsum[w]; }
        }
        __syncthreads();
        int ex = incl - tot4 + woff[t >> 6];
        int nodebase = pbase + ex;
        curL[t] = nodebase;
        curH[t] = nodebase + c4l;
        if (valid) {
            rowptr4[node] = nodebase;
            cnts[node] = cl | (ch << 16);
            csr_src[selfLow ? (nodebase + hl) : (nodebase + c4l + (h - hl))] = node;
        }
    }
    __syncthreads();
    for (int j = t; j < cnt; j += 256) {
        int v = inl ? ebuf[j] : packed[base_in + j];
        int nid = v >> 17;
        int srcv = v & 0x1FFFF;
        int off = (srcv < NHALF) ? atomicAdd(&curL[nid], 1) : atomicAdd(&curH[nid], 1);
        csr_src[off] = srcv;
    }
}

// ============ per-edge normalized attention over the split list =======
// packed2[slot] = (src<<15)|q15(alpha); pads: low half src=0, high src=NHALF.
__global__ __launch_bounds__(256) void gat_alpha(const int* __restrict__ rowptr4,
                                                 const int* __restrict__ cnts,
                                                 const int* __restrict__ csr,
                                                 const float* __restrict__ s,
                                                 const float* __restrict__ d,
                                                 unsigned* __restrict__ packed2, int n) {
    int node = blockIdx.x * 8 + (threadIdx.x >> 5);
    if (node >= n) return;
    int lane = threadIdx.x & 31;
    int base = rowptr4[node];
    int cw = cnts[node];
    int cl = cw & 0xFFFF, ch = cw >> 16;
    int c4l = (cl + 3) & ~3, c4h = (ch + 3) & ~3;
    int tot = c4l + c4h;
    float dnode = d[node];

    if (tot <= 32) {
        bool real = (lane < cl) || (lane >= c4l && lane < c4l + ch);
        int si = real ? csr[base + lane] : 0;
        float lv = real ? leaky02(s[si] + dnode) : -1e30f;
        float lm = lv;
#pragma unroll
        for (int off = 16; off; off >>= 1) lm = fmaxf(lm, __shfl_xor(lm, off));
        float w = real ? expf(lv - lm) : 0.f;
        float denom = w;
#pragma unroll
        for (int off = 16; off; off >>= 1) denom += __shfl_xor(denom, off);
        if (lane < tot) {
            unsigned pk = real ? (((unsigned)si << 15) |
                                  (unsigned)__float2int_rn(w / denom * 32767.f))
                               : (lane < c4l ? 0u : ((unsigned)NHALF << 15));
            packed2[base + lane] = pk;
        }
    } else {
        float m = -1e30f;
        for (int c = 0; c < tot; c += 32) {
            int idx = c + lane;
            bool real = (idx < cl) || (idx >= c4l && idx < c4l + ch);
            int si = real ? csr[base + idx] : 0;
            float lv = real ? leaky02(s[si] + dnode) : -1e30f;
            m = fmaxf(m, lv);
        }
#pragma unroll
        for (int off = 16; off; off >>= 1) m = fmaxf(m, __shfl_xor(m, off));
        float denom = 0.f;
        for (int c = 0; c < tot; c += 32) {
            int idx = c + lane;
            bool real = (idx < cl) || (idx >= c4l && idx < c4l + ch);
            int si = real ? csr[base + idx] : 0;
            if (real) denom += expf(leaky02(s[si] + dnode) - m);
        }
#pragma unroll
        for (int off = 16; off; off >>= 1) denom += __shfl_xor(denom, off);
        for (int c = 0; c < tot; c += 32) {
            int idx = c + lane;
            if (idx < tot) {
                bool real = (idx < cl) || (idx >= c4l && idx < c4l + ch);
                int si = real ? csr[base + idx] : 0;
                unsigned pk;
                if (real) {
                    float w = expf(leaky02(s[si] + dnode) - m);
                    pk = ((unsigned)si << 15) |
                         (unsigned)__float2int_rn(w / denom * 32767.f);
                } else {
                    pk = (idx < c4l) ? 0u : ((unsigned)NHALF << 15);
                }
                packed2[base + idx] = pk;
            }
        }
    }
}

// ============ grouped aggregation, src-split two-pass (4-slot, R18) ===
// group = blockIdx & 3; pass 0: low-src half -> partial in A16 (no bias);
// pass 1: high-src half + partial -> bias + relu -> A16.
// Per (group,pass) H working set = 50k x 64B = 3.2MB -> L2-resident.
template <int PASS>
__global__ __launch_bounds__(256) void gat_agg(const int* __restrict__ rowptr4,
                                               const int* __restrict__ cnts,
                                               const unsigned* __restrict__ packed2,
                                               const __half* __restrict__ H,
                                               const float* __restrict__ bias,
                                               __half* __restrict__ A16, int n) {
    int grp = blockIdx.x & 3;
    int blk = blockIdx.x >> 2;
    int wid = threadIdx.x >> 6;
    int lane = threadIdx.x & 63;
    int nd = lane >> 2;                  // node slot 0..15
    int cg = lane & 3;                   // col sub-group: 8 cols (16B)
    int node = blk * 64 + wid * 16 + nd;
    if (node >= n) return;
    const __half* Hs = H + (size_t)grp * NGR32 + cg * 8;
    __half* As = A16 + (size_t)grp * NGR32;

    int base = rowptr4[node];
    int cw   = cnts[node];
    int cl = cw & 0xFFFF, ch = cw >> 16;
    int iters, off0;
    if (PASS == 0) { iters = (cl + 3) >> 2; off0 = 0; }
    else           { iters = (ch + 3) >> 2; off0 = (cl + 3) & ~3; }
    const uint4* p = (const uint4*)(packed2 + base + off0);

    // pass-1: partial load (independent, overlaps the loop)
    H16u part;
    if (PASS == 1) part.u = *(const uint4*)(As + (size_t)node * 32 + cg * 8);

    float acc[8] = {0.f, 0.f, 0.f, 0.f, 0.f, 0.f, 0.f, 0.f};
    uint4 q = p[0];
    for (int it = 0; it < iters; ++it) {
        uint4 nq = p[it + 1];            // prefetch (16B overread ok: pad slack)
        float a0 = (float)(q.x & 0x7fffu);
        float a1 = (float)(q.y & 0x7fffu);
        float a2 = (float)(q.z & 0x7fffu);
        float a3 = (float)(q.w & 0x7fffu);
        H16u h0, h1, h2, h3;
        h0.u = *(const uint4*)(Hs + (size_t)(q.x >> 15) * 32);
        h1.u = *(const uint4*)(Hs + (size_t)(q.y >> 15) * 32);
        h2.u = *(const uint4*)(Hs + (size_t)(q.z >> 15) * 32);
        h3.u = *(const uint4*)(Hs + (size_t)(q.w >> 15) * 32);
#pragma unroll
        for (int c2 = 0; c2 < 4; ++c2) {
            float2 f0 = __half22float2(h0.h[c2]);
            float2 f1 = __half22float2(h1.h[c2]);
            float2 f2 = __half22float2(h2.h[c2]);
            float2 f3 = __half22float2(h3.h[c2]);
            acc[c2 * 2 + 0] += a0 * f0.x + a1 * f1.x + a2 * f2.x + a3 * f3.x;
            acc[c2 * 2 + 1] += a0 * f0.y + a1 * f1.y + a2 * f2.y + a3 * f3.y;
        }
        q = nq;
    }
    const float scale = 1.f / 32767.f;
    H16u pk16;
    if (PASS == 0) {
#pragma unroll
        for (int c2 = 0; c2 < 4; ++c2)
            pk16.h[c2] = __floats2half2_rn(acc[c2 * 2 + 0] * scale,
                                           acc[c2 * 2 + 1] * scale);
    } else {
        int cb = grp * 32 + cg * 8;
#pragma unroll
        for (int c2 = 0; c2 < 4; ++c2) {
            float2 pv = __half22float2(part.h[c2]);
            float o0 = fmaxf(pv.x + acc[c2 * 2 + 0] * scale + bias[cb + c2 * 2 + 0], 0.f);
            float o1 = fmaxf(pv.y + acc[c2 * 2 + 1] * scale + bias[cb + c2 * 2 + 1], 0.f);
            pk16.h[c2] = __floats2half2_rn(o0, o1);
        }
    }
    *(uint4*)(As + (size_t)node * 32 + cg * 8) = pk16.u;
}

// ============ classifier: out = A16 @ Wc + bc  (A16 group-major) ======
__global__ __launch_bounds__(256) void classify16(const __half* __restrict__ A,
                                                  const float* __restrict__ Wc,
                                                  const float* __restrict__ bc,
                                                  float* __restrict__ out, int n) {
    int node = blockIdx.x * 4 + (threadIdx.x >> 6);
    if (node >= n) return;
    int lane = threadIdx.x & 63;
    int col = lane * 2;
    int g = col >> 5, off = col & 31;
    __half2 h2 = *(const __half2*)(A + (size_t)g * NGR32 + (size_t)node * 32 + off);
    float2 f = __half22float2(h2);
    float o0 = f.x * Wc[col * 2]       + f.y * Wc[(col + 1) * 2];
    float o1 = f.x * Wc[col * 2 + 1]   + f.y * Wc[(col + 1) * 2 + 1];
#pragma unroll
    for (int offx = 32; offx; offx >>= 1) {
        o0 += __shfl_xor(o0, offx);
        o1 += __shfl_xor(o1, offx);
    }
    if (lane == 0) {
        out[(size_t)node * 2 + 0] = o0 + bc[0];
        out[(size_t)node * 2 + 1] = o1 + bc[1];
    }
}

extern "C" void kernel_launch(void* const* d_in, const int* in_sizes, int n_in,
                              void* d_out, int out_size, void* d_ws, size_t ws_size,
                              hipStream_t stream) {
    const float* x   = (const float*)d_in[0];
    const int*   ei  = (const int*)d_in[1];
    const int*   src = ei;
    const int*   dst = ei + NEDGES;
    const float* Ws[3]  = {(const float*)d_in[2], (const float*)d_in[6], (const float*)d_in[10]};
    const float* ass[3] = {(const float*)d_in[3], (const float*)d_in[7], (const float*)d_in[11]};
    const float* ads[3] = {(const float*)d_in[4], (const float*)d_in[8], (const float*)d_in[12]};
    const float* bs[3]  = {(const float*)d_in[5], (const float*)d_in[9], (const float*)d_in[13]};
    const float* Wc = (const float*)d_in[14];
    const float* bc = (const float*)d_in[15];
    float* out = (float*)d_out;

    const int n = NNODES;

    // ---- workspace (~80 MB) ----
    __half*   h16  = (__half*)d_ws;                     // N*128 fp16 (group-major)
    __half*   a16  = h16 + (size_t)n * DIM;             // N*128 fp16 (group-major)
    __half*   wt16 = a16 + (size_t)n * DIM;             // 3*128*128 fp16 (W^T)
    float*    sbuf = (float*)(wt16 + 3 * 128 * 128);    // N
    float*    dbuf = sbuf + n;                          // N
    int*      rowptr4     = (int*)(dbuf + n);           // N
    int*      cnts        = rowptr4 + n;                // N
    int*      csr_src     = cnts + n;                   // CSRSZ
    unsigned* packed2     = (unsigned*)(csr_src + CSRSZ); // CSRSZ
    int*      packed      = (int*)(packed2 + CSRSZ);    // E (build temp)
    int*      blockcounts = packed + NEDGES;            // NBK*NCH
    int*      bbase       = blockcounts + (size_t)NBK * NCH; // NBK+1
    int*      btotal      = bbase + NBK + 1;            // NBK

    const int g64        = (n + 63) / 64;
    const int alpha_grid = (n + 7) / 8;           // 12500
    const int cls_grid   = (n + 3) / 4;           // 25000
    const int agg_grid   = ((n + 63) / 64) * 4;   // 6252

    // ---- one-time prep ----
    wprep<<<192, 256, 0, stream>>>(Ws[0], Ws[1], Ws[2], wt16);
    bucket_count<<<NCH, 512, 0, stream>>>(dst, blockcounts);
    bucket_scan_a<<<NBK, NCH, 0, stream>>>(blockcounts, btotal);
    bucket_scan_b<<<1, 512, 0, stream>>>(btotal, bbase);
    bucket_scatter<<<NCH, 512, 0, stream>>>(src, dst, blockcounts, bbase, packed);
    bucket_csr<<<NBK, 256, 0, stream>>>(packed, bbase, rowptr4, cnts, csr_src);

    // ---- 3 GAT layers ----
    for (int layer = 0; layer < 3; ++layer) {
        const __half* wl = wt16 + (size_t)layer * 128 * 128;
        if (layer == 0)
            gemm_mfma<false><<<g64, 256, 0, stream>>>(x, a16, wl, ass[0], ads[0],
                                                      h16, sbuf, dbuf, n);
        else
            gemm_mfma<true><<<g64, 256, 0, stream>>>(x, a16, wl, ass[layer], ads[layer],
                                                     h16, sbuf, dbuf, n);
        gat_alpha<<<alpha_grid, 256, 0, stream>>>(rowptr4, cnts, csr_src, sbuf, dbuf,
                                                  packed2, n);
        gat_agg<0><<<agg_grid, 256, 0, stream>>>(rowptr4, cnts, packed2, h16, bs[layer], a16, n);
        gat_agg<1><<<agg_grid, 256, 0, stream>>>(rowptr4, cnts, packed2, h16, bs[layer], a16, n);
    }
    classify16<<<cls_grid, 256, 0, stream>>>(a16, Wc, bc, out, n);
}